// Round 4
// baseline (1015.808 us; speedup 1.0000x reference)
//
#include <hip/hip_runtime.h>
#include <stdint.h>

typedef unsigned short u16;
typedef short s16x8 __attribute__((ext_vector_type(8)));
typedef float f32x4 __attribute__((ext_vector_type(4)));

__device__ __forceinline__ u16 f2bf(float f) {
    union { float f; uint32_t i; } v; v.f = f;
    return (u16)((v.i + 0x7FFFu + ((v.i >> 16) & 1u)) >> 16);
}

__global__ void __launch_bounds__(256) cvt_f32_bf16(
    const float* __restrict__ src, u16* __restrict__ dst, int n4)
{
    int i = blockIdx.x * 256 + threadIdx.x;
    if (i >= n4) return;
    float4 f = ((const float4*)src)[i];
    ushort4 o;
    o.x = f2bf(f.x); o.y = f2bf(f.y); o.z = f2bf(f.z); o.w = f2bf(f.w);
    ((ushort4*)dst)[i] = o;
}

#define ASYNC_LD16(gp, lp)                                                       \
    __builtin_amdgcn_global_load_lds(                                            \
        (const __attribute__((address_space(1))) uint32_t*)(gp),                 \
        (__attribute__((address_space(3))) uint32_t*)(lp), 16, 0, 0)

// ---------------------------------------------------------------------------
// Small-GEMM kernel (verified): 128x128 tile, single-buffered.
// MODE 0: c += bias[col]; e=exp(c); store bf16; atomicAdd row-sums of e.
// MODE 1: c += bias[row]; store bf16 relu(c).
template <int MODE>
__global__ void __launch_bounds__(256) gemm_bt(
    const u16* __restrict__ A, const u16* __restrict__ B, int K, int N,
    u16* __restrict__ C, float* __restrict__ Cf,
    const float* __restrict__ bias,
    const float* __restrict__ sv, float* __restrict__ sum_out)
{
    __shared__ __align__(16) u16 As[128 * 32];
    __shared__ __align__(16) u16 Bs[128 * 32];

    const int tid  = threadIdx.x;
    const int lane = tid & 63;
    const int wave = tid >> 6;
    const int wx = wave & 1, wy = wave >> 1;
    const int lr = lane & 15, lq = lane >> 4;
    const int m0 = blockIdx.y * 128, n0 = blockIdx.x * 128;

    f32x4 acc[4][4] = {};

    const int srow = tid >> 2;
    const int scol = (tid & 3) * 8;
    const u16* gA = A + (size_t)(m0 + srow) * K + scol;
    const u16* gB = B + (size_t)(n0 + srow) * K + scol;
    const size_t rstep = (size_t)64 * K;
    u16* lA0 = &As[wave * 512];
    u16* lA1 = &As[2048 + wave * 512];
    u16* lB0 = &Bs[wave * 512];
    u16* lB1 = &Bs[2048 + wave * 512];

    const u16* pa = &As[(wy * 64 + lr) * 32 + lq * 8];
    const u16* pb = &Bs[(wx * 64 + lr) * 32 + lq * 8];

    for (int k0 = 0; k0 < K; k0 += 32) {
        ASYNC_LD16(gA + k0, lA0);
        ASYNC_LD16(gA + k0 + rstep, lA1);
        ASYNC_LD16(gB + k0, lB0);
        ASYNC_LD16(gB + k0 + rstep, lB1);
        __syncthreads();
        s16x8 af[4], bfr[4];
#pragma unroll
        for (int i = 0; i < 4; ++i) {
            af[i]  = *(const s16x8*)(pa + i * 512);
            bfr[i] = *(const s16x8*)(pb + i * 512);
        }
#pragma unroll
        for (int mi = 0; mi < 4; ++mi)
#pragma unroll
            for (int ni = 0; ni < 4; ++ni)
                acc[mi][ni] = __builtin_amdgcn_mfma_f32_16x16x32_bf16(
                    af[mi], bfr[ni], acc[mi][ni], 0, 0, 0);
        __syncthreads();
    }

    const int rowB = m0 + wy * 64 + lq * 4;
    const int colB = n0 + wx * 64 + lr;

    if constexpr (MODE == 0) {
        float bcol[4];
#pragma unroll
        for (int ni = 0; ni < 4; ++ni) bcol[ni] = bias[colB + ni * 16];
#pragma unroll
        for (int mi = 0; mi < 4; ++mi)
#pragma unroll
            for (int r = 0; r < 4; ++r) {
                const int gm = rowB + mi * 16 + r;
                float s = 0.f;
#pragma unroll
                for (int ni = 0; ni < 4; ++ni) {
                    float e = __expf(acc[mi][ni][r] + bcol[ni]);
                    C[(size_t)gm * N + (colB + ni * 16)] = f2bf(e);
                    s += e;
                }
                s += __shfl_xor(s, 1);
                s += __shfl_xor(s, 2);
                s += __shfl_xor(s, 4);
                s += __shfl_xor(s, 8);
                if (lr == 0) atomicAdd(&sum_out[gm], s);
            }
    } else {
#pragma unroll
        for (int mi = 0; mi < 4; ++mi)
#pragma unroll
            for (int r = 0; r < 4; ++r) {
                const int gm = rowB + mi * 16 + r;
                const float b = bias[gm];
#pragma unroll
                for (int ni = 0; ni < 4; ++ni) {
                    float c = acc[mi][ni][r] + b;
                    C[(size_t)gm * N + (colB + ni * 16)] = f2bf(c > 0.f ? c : 0.f);
                }
            }
    }
}

// ---------------------------------------------------------------------------
// Big-GEMM kernel v4: 128x128 tile, 4 waves (256 thr), per-wave 64x64
// (acc[4][4] = 64 AGPR), BK=32, 3-deep LDS ring (48 KiB) => 3 blocks/CU,
// ~12 waves/CU: inter-block TLP hides staging waits (m97/m114 mechanism).
// Counted vmcnt(4) (one K-tile always in flight, never drained to 0),
// ONE barrier per K-tile, conflict-free both-sides XOR swizzle (verified:
// 0 bank conflicts in rounds 1-3), XCD-aware bijective block swizzle.
//
// Race-freedom:
//   RAW: end of iter c waits vmcnt(4); outstanding then = tile (c+2)'s 4
//        loads only => tile c+1 fully in LDS; barrier publishes before any
//        wave reads buf (c+1)%3 in iter c+1. Prologue: 8 loads, vmcnt(4)
//        => tile 0 landed before iter 0.
//   WAR: STG(c+2) targets buf (c+2)%3 == buf (c-1)%3, issued after barrier
//        B_{c-1}; every wave's ds_reads of that buf were lgkm-waited before
//        its MFMA uses in iter c-1, which precede B_{c-1}.
// MODE 2: e = exp(c / sv[col]); store bf16; atomicAdd row-sums of e.
// MODE 3: store fp32 (c / sv[row]) to Cf.
template <int MODE>
__global__ void __launch_bounds__(256, 3) gemm128p_bt(
    const u16* __restrict__ A, const u16* __restrict__ B, int K, int N,
    u16* __restrict__ C, float* __restrict__ Cf,
    const float* __restrict__ sv, float* __restrict__ sum_out, int nbx)
{
    __shared__ __align__(16) u16 lds[3 * 8192];   // 3 bufs x (A 8KB + B 8KB)

    const int tid  = threadIdx.x;
    const int lane = tid & 63;
    const int wave = tid >> 6;          // 0..3
    const int wr = wave >> 1;           // 0..1 : 64-row half
    const int wc = wave & 1;            // 0..1 : 64-col half
    const int fr = lane & 15;
    const int lq = lane >> 4;

    // XCD-aware bijective swizzle (gridDim.x % 8 == 0 for both uses)
    const int nwg = gridDim.x;
    const int swz = ((int)blockIdx.x & 7) * (nwg >> 3) + ((int)blockIdx.x >> 3);
    const int bx = swz % nbx, by = swz / nbx;
    const int m0 = by * 128, n0 = bx * 128;

    // staging: linear LDS dest, pre-swizzled global source.
    // LDS slot (row, c2) holds global chunk  c2 ^ ((row>>1)&3).
    // Thread t covers chunk slots (r0 = t>>2, c2 = t&3) and (r0+64, c2);
    // ((r0+64)>>1)&3 == (r0>>1)&3, so the same gch works for both rounds.
    const int r0  = tid >> 2;           // 0..63
    const int gch = (tid & 3) ^ ((r0 >> 1) & 3);
    const u16* gA0 = A + (size_t)(m0 + r0) * K + gch * 8;
    const u16* gA1 = A + (size_t)(m0 + r0 + 64) * K + gch * 8;
    const u16* gB0 = B + (size_t)(n0 + r0) * K + gch * 8;
    const u16* gB1 = B + (size_t)(n0 + r0 + 64) * K + gch * 8;

    // LDS dests are wave-uniform base + lane*16B (global_load_lds rule);
    // byte offset for thread t's slot l = t (or 256+t) is exactly l*16.
#define STG(bf_, kt_) do {                                                    \
        ASYNC_LD16(gA0 + (kt_) * 32, lds + (bf_) * 8192 + wave * 512);        \
        ASYNC_LD16(gA1 + (kt_) * 32, lds + (bf_) * 8192 + 2048 + wave * 512); \
        ASYNC_LD16(gB0 + (kt_) * 32, lds + (bf_) * 8192 + 4096 + wave * 512); \
        ASYNC_LD16(gB1 + (kt_) * 32, lds + (bf_) * 8192 + 6144 + wave * 512); \
    } while (0)

    // fragment reads: global chunk lq of row -> LDS chunk lq ^ ((row>>1)&3);
    // row = wr*64 + mi*16 + fr => (row>>1)&3 == (fr>>1)&3 (constant per lane).
    const int rch  = lq ^ ((fr >> 1) & 3);
    const int offA = (wr * 64 + fr) * 32 + rch * 8;            // + mi*512
    const int offB = 4096 + (wc * 64 + fr) * 32 + rch * 8;     // + ni*512

    f32x4 acc[4][4] = {};
    const int NT = K >> 5;              // K-tiles of 32 (>= 4 here)

    // prologue: stage K-tiles 0,1 (8 loads in flight)
    STG(0, 0);
    STG(1, 1);
    asm volatile("s_waitcnt vmcnt(4)" ::: "memory");   // K-tile 0 landed
    __builtin_amdgcn_s_barrier();

    int cur = 0, stg = 2;
    for (int c = 0; c < NT; ++c) {
        const u16* s = lds + cur * 8192;
        if (c + 2 < NT) STG(stg, c + 2);
        s16x8 a[4], b[4];
#pragma unroll
        for (int i = 0; i < 4; ++i) a[i] = *(const s16x8*)(s + offA + i * 512);
#pragma unroll
        for (int i = 0; i < 4; ++i) b[i] = *(const s16x8*)(s + offB + i * 512);
        __builtin_amdgcn_s_setprio(1);
#pragma unroll
        for (int mi = 0; mi < 4; ++mi)
#pragma unroll
            for (int ni = 0; ni < 4; ++ni)
                acc[mi][ni] = __builtin_amdgcn_mfma_f32_16x16x32_bf16(
                    a[mi], b[ni], acc[mi][ni], 0, 0, 0);
        __builtin_amdgcn_s_setprio(0);
        asm volatile("s_waitcnt vmcnt(4)" ::: "memory");   // K-tile c+1 landed
        __builtin_amdgcn_s_barrier();
        cur = (cur == 2) ? 0 : cur + 1;
        stg = (stg == 2) ? 0 : stg + 1;
    }

    // epilogue. C/D layout: row = lq*4 + reg (+16*mi), col = fr (+16*ni)
    const int rowB = m0 + wr * 64 + lq * 4;
    const int colB = n0 + wc * 64 + fr;

    if constexpr (MODE == 2) {
        float inv[4];
#pragma unroll
        for (int ni = 0; ni < 4; ++ni) inv[ni] = 1.0f / sv[colB + ni * 16];
#pragma unroll
        for (int mi = 0; mi < 4; ++mi)
#pragma unroll
            for (int r = 0; r < 4; ++r) {
                const int gm = rowB + mi * 16 + r;
                float s = 0.f;
#pragma unroll
                for (int ni = 0; ni < 4; ++ni) {
                    float e = __expf(acc[mi][ni][r] * inv[ni]);
                    C[(size_t)gm * N + (colB + ni * 16)] = f2bf(e);
                    s += e;
                }
                s += __shfl_xor(s, 1);
                s += __shfl_xor(s, 2);
                s += __shfl_xor(s, 4);
                s += __shfl_xor(s, 8);
                if (fr == 0) atomicAdd(&sum_out[gm], s);
            }
    } else {  // MODE 3: fp32 out, divide by row sum
#pragma unroll
        for (int mi = 0; mi < 4; ++mi)
#pragma unroll
            for (int r = 0; r < 4; ++r) {
                const int gm = rowB + mi * 16 + r;
                const float invr = 1.0f / sv[gm];
#pragma unroll
                for (int ni = 0; ni < 4; ++ni)
                    Cf[(size_t)gm * N + (colB + ni * 16)] = acc[mi][ni][r] * invr;
            }
    }
#undef STG
}

extern "C" void kernel_launch(void* const* d_in, const int* in_sizes, int n_in,
                              void* d_out, int out_size, void* d_ws, size_t ws_size,
                              hipStream_t stream)
{
    (void)in_sizes; (void)n_in; (void)out_size;
    const float* kin = (const float*)d_in[0];   // 32768 x 1024 fp32
    const float* mem = (const float*)d_in[1];   // 4096 x 512
    const float* fkw = (const float*)d_in[2];   // 1024 x 512
    const float* fkb = (const float*)d_in[3];   // 1024
    const float* fvw = (const float*)d_in[4];   // 1024 x 512
    const float* fvb = (const float*)d_in[5];   // 1024
    float* out = (float*)d_out;                 // 32768 x 1024 fp32

    const int NM = 4096, MD = 512, ID = 1024, NQ = 32768;

    u16* kbf   = (u16*)d_ws;                          // NQ x ID   (64 MB)
    u16* membf = kbf   + (size_t)NQ * ID;             // NM x MD   (4 MB)
    u16* fkwbf = membf + (size_t)NM * MD;             // ID x MD   (1 MB)
    u16* fvwbf = fkwbf + (size_t)ID * MD;             // ID x MD   (1 MB)
    u16* expK  = fvwbf + (size_t)ID * MD;             // NM x ID   (8 MB)
    u16* valT  = expK  + (size_t)NM * ID;             // ID x NM   (8 MB)
    u16* P     = valT  + (size_t)ID * NM;             // NQ x NM   (256 MB)
    float* rsK = (float*)(P + (size_t)NQ * NM);       // NM
    float* rs2 = rsK + NM;                            // NQ
    const size_t needed = (size_t)((char*)(rs2 + NQ) - (char*)d_ws);
    if (ws_size < needed) return;  // diagnostic: absmax == 0.2676 exactly

    hipMemsetAsync(rsK, 0, (size_t)(NM + NQ) * sizeof(float), stream);

    // fp32 -> bf16 converts
    cvt_f32_bf16<<<(NQ * ID / 4 + 255) / 256, 256, 0, stream>>>(kin, kbf, NQ * ID / 4);
    cvt_f32_bf16<<<(NM * MD / 4 + 255) / 256, 256, 0, stream>>>(mem, membf, NM * MD / 4);
    cvt_f32_bf16<<<(ID * MD / 4 + 255) / 256, 256, 0, stream>>>(fkw, fkwbf, ID * MD / 4);
    cvt_f32_bf16<<<(ID * MD / 4 + 255) / 256, 256, 0, stream>>>(fvw, fvwbf, ID * MD / 4);

    // K1a: expK[m,i] = exp(mem @ fk_w^T + fk_b[i]); rsK[m] = row sums
    gemm_bt<0><<<dim3(ID / 128, NM / 128), 256, 0, stream>>>(
        membf, fkwbf, MD, ID, expK, nullptr, fkb, nullptr, rsK);
    // K1b: valT[i,m] = relu(fv_w @ mem^T + fv_b[i])
    gemm_bt<1><<<dim3(NM / 128, ID / 128), 256, 0, stream>>>(
        fvwbf, membf, MD, NM, valT, nullptr, fvb, nullptr, nullptr);
    // K2: P[q,m] = exp((k @ expK^T)[q,m] / rsK[m]); rs2[q] = row sums
    gemm128p_bt<2><<<(NQ / 128) * (NM / 128), 256, 0, stream>>>(
        kbf, expK, ID, NM, P, nullptr, rsK, rs2, NM / 128);
    // K3: out[q,i] = (P @ valT^T)[q,i] / rs2[q]
    gemm128p_bt<3><<<(NQ / 128) * (ID / 128), 256, 0, stream>>>(
        P, valT, NM, ID, nullptr, out, rs2, nullptr, ID / 128);
}

// Round 5
// 1012.771 us; speedup vs baseline: 1.0030x; 1.0030x over previous
//
#include <hip/hip_runtime.h>
#include <stdint.h>

typedef unsigned short u16;
typedef short s16x8 __attribute__((ext_vector_type(8)));
typedef float f32x4 __attribute__((ext_vector_type(4)));

__device__ __forceinline__ u16 f2bf(float f) {
    union { float f; uint32_t i; } v; v.f = f;
    return (u16)((v.i + 0x7FFFu + ((v.i >> 16) & 1u)) >> 16);
}

__global__ void __launch_bounds__(256) cvt_f32_bf16(
    const float* __restrict__ src, u16* __restrict__ dst, int n4)
{
    int i = blockIdx.x * 256 + threadIdx.x;
    if (i >= n4) return;
    float4 f = ((const float4*)src)[i];
    ushort4 o;
    o.x = f2bf(f.x); o.y = f2bf(f.y); o.z = f2bf(f.z); o.w = f2bf(f.w);
    ((ushort4*)dst)[i] = o;
}

#define ASYNC_LD16(gp, lp)                                                       \
    __builtin_amdgcn_global_load_lds(                                            \
        (const __attribute__((address_space(1))) uint32_t*)(gp),                 \
        (__attribute__((address_space(3))) uint32_t*)(lp), 16, 0, 0)

// ---------------------------------------------------------------------------
// Small-GEMM kernel (verified): 128x128 tile, single-buffered.
// MODE 0: c += bias[col]; e=exp(c); store bf16; atomicAdd row-sums of e.
// MODE 1: c += bias[row]; store bf16 relu(c).
template <int MODE>
__global__ void __launch_bounds__(256) gemm_bt(
    const u16* __restrict__ A, const u16* __restrict__ B, int K, int N,
    u16* __restrict__ C, float* __restrict__ Cf,
    const float* __restrict__ bias,
    const float* __restrict__ sv, float* __restrict__ sum_out)
{
    __shared__ __align__(16) u16 As[128 * 32];
    __shared__ __align__(16) u16 Bs[128 * 32];

    const int tid  = threadIdx.x;
    const int lane = tid & 63;
    const int wave = tid >> 6;
    const int wx = wave & 1, wy = wave >> 1;
    const int lr = lane & 15, lq = lane >> 4;
    const int m0 = blockIdx.y * 128, n0 = blockIdx.x * 128;

    f32x4 acc[4][4] = {};

    const int srow = tid >> 2;
    const int scol = (tid & 3) * 8;
    const u16* gA = A + (size_t)(m0 + srow) * K + scol;
    const u16* gB = B + (size_t)(n0 + srow) * K + scol;
    const size_t rstep = (size_t)64 * K;
    u16* lA0 = &As[wave * 512];
    u16* lA1 = &As[2048 + wave * 512];
    u16* lB0 = &Bs[wave * 512];
    u16* lB1 = &Bs[2048 + wave * 512];

    const u16* pa = &As[(wy * 64 + lr) * 32 + lq * 8];
    const u16* pb = &Bs[(wx * 64 + lr) * 32 + lq * 8];

    for (int k0 = 0; k0 < K; k0 += 32) {
        ASYNC_LD16(gA + k0, lA0);
        ASYNC_LD16(gA + k0 + rstep, lA1);
        ASYNC_LD16(gB + k0, lB0);
        ASYNC_LD16(gB + k0 + rstep, lB1);
        __syncthreads();
        s16x8 af[4], bfr[4];
#pragma unroll
        for (int i = 0; i < 4; ++i) {
            af[i]  = *(const s16x8*)(pa + i * 512);
            bfr[i] = *(const s16x8*)(pb + i * 512);
        }
#pragma unroll
        for (int mi = 0; mi < 4; ++mi)
#pragma unroll
            for (int ni = 0; ni < 4; ++ni)
                acc[mi][ni] = __builtin_amdgcn_mfma_f32_16x16x32_bf16(
                    af[mi], bfr[ni], acc[mi][ni], 0, 0, 0);
        __syncthreads();
    }

    const int rowB = m0 + wy * 64 + lq * 4;
    const int colB = n0 + wx * 64 + lr;

    if constexpr (MODE == 0) {
        float bcol[4];
#pragma unroll
        for (int ni = 0; ni < 4; ++ni) bcol[ni] = bias[colB + ni * 16];
#pragma unroll
        for (int mi = 0; mi < 4; ++mi)
#pragma unroll
            for (int r = 0; r < 4; ++r) {
                const int gm = rowB + mi * 16 + r;
                float s = 0.f;
#pragma unroll
                for (int ni = 0; ni < 4; ++ni) {
                    float e = __expf(acc[mi][ni][r] + bcol[ni]);
                    C[(size_t)gm * N + (colB + ni * 16)] = f2bf(e);
                    s += e;
                }
                s += __shfl_xor(s, 1);
                s += __shfl_xor(s, 2);
                s += __shfl_xor(s, 4);
                s += __shfl_xor(s, 8);
                if (lr == 0) atomicAdd(&sum_out[gm], s);
            }
    } else {
#pragma unroll
        for (int mi = 0; mi < 4; ++mi)
#pragma unroll
            for (int r = 0; r < 4; ++r) {
                const int gm = rowB + mi * 16 + r;
                const float b = bias[gm];
#pragma unroll
                for (int ni = 0; ni < 4; ++ni) {
                    float c = acc[mi][ni][r] + b;
                    C[(size_t)gm * N + (colB + ni * 16)] = f2bf(c > 0.f ? c : 0.f);
                }
            }
    }
}

// ---------------------------------------------------------------------------
// Big-GEMM kernel v5: 256x256 tile, 8 waves, BK=64, 2-deep dbuf (128 KiB),
// FINE-GRAINED 4-phase schedule per K-tile (the T3/T4 structure):
//   phase = { ds_read next phase's frags | barrier | setprio(1) |
//             16 MFMA | setprio(0) | barrier }
//   - A frags ping-pong 2 register sets; B frags (both k-halves) live the
//     whole tile (24 ds_read_b128 per tile per wave, not 32).
//   - staging: 8 global_load_lds per thread, once per tile at ph3, into the
//     buffer currently being read (tile c+2 -> buf c&1); then vmcnt(8)
//     (counted; tile c+1's 8 loads are the oldest -> proven landed).
//     Prefetch distance = 4 phases (~2.5k cyc) >> HBM latency.
// Race-freedom:
//   RAW: at ph3 of tile c, after issuing c+2's 8 loads, vmcnt(8) leaves only
//        those 8 outstanding => c+1's 8 loads landed; trailing barrier
//        publishes before any wave reads buf (c+1)&1 at ph0 of c+1.
//        Prologue: stage tiles 0,1 (16 loads), vmcnt(8) => tile 0 landed.
//   WAR: staging c+2 -> buf c&1 issues at ph3, after every wave issued all
//        its reads of buf c&1 (done by ph2; barrier-ordered); LDS write
//        lands >=200cy after issue, reads serviced ~tens of cy after theirs.
// MODE 2: e = exp(c / sv[col]); store bf16; atomicAdd row-sums of e.
// MODE 3: store fp32 (c / sv[row]) to Cf.
template <int MODE>
__global__ void __launch_bounds__(512, 2) gemm256_bt(
    const u16* __restrict__ A, const u16* __restrict__ B, int K, int N,
    u16* __restrict__ C, float* __restrict__ Cf,
    const float* __restrict__ sv, float* __restrict__ sum_out, int nbx)
{
    __shared__ __align__(16) u16 lds[2 * 32768];   // 2 bufs x (A 32KB + B 32KB)

    const int tid  = threadIdx.x;
    const int lane = tid & 63;
    const int wave = tid >> 6;          // 0..7
    const int wr = wave >> 2;           // 0..1 : 128-row half of C
    const int wc = wave & 3;            // 0..3 : 64-col quarter of C
    const int fr = lane & 15;
    const int lq = lane >> 4;

    // XCD-aware bijective swizzle (gridDim.x % 8 == 0 for both uses)
    const int nwg = gridDim.x;
    const int swz = ((int)blockIdx.x & 7) * (nwg >> 3) + ((int)blockIdx.x >> 3);
    const int bx = swz % nbx, by = swz / nbx;
    const int m0 = by * 256, n0 = bx * 256;

    // ---- staging: linear LDS dest, pre-swizzled global source.
    // A tile in LDS: 256 rows x 8 chunks(16B). slot l = j*512 + tid (j=0..3);
    // row = l>>3 = j*64 + (tid>>3), c2 = l&7.  LDS(row,c2) holds global chunk
    // c2 ^ ((row>>1)&7); (row>>1)&7 == (tid>>4)&7 (j*32 = 0 mod 8).
    const int gch = (tid & 7) ^ ((tid >> 4) & 7);
    const u16* gAb = A + (size_t)(m0 + (tid >> 3)) * K + gch * 8;
    const u16* gBb = B + (size_t)(n0 + (tid >> 3)) * K + gch * 8;
    const size_t rst64 = (size_t)64 * K;   // +64 rows

    // LDS dest (u16 units): A: buf + j*4096 + wave*512 ; B: +16384.
#define STG(bf_, kt_) do {                                                    \
        const u16* _a = gAb + (size_t)(kt_) * 64;                             \
        const u16* _b = gBb + (size_t)(kt_) * 64;                             \
        u16* _lA = lds + (bf_) * 32768 + wave * 512;                          \
        u16* _lB = _lA + 16384;                                               \
        ASYNC_LD16(_a,             _lA);                                      \
        ASYNC_LD16(_a + rst64,     _lA + 4096);                               \
        ASYNC_LD16(_a + 2 * rst64, _lA + 8192);                               \
        ASYNC_LD16(_a + 3 * rst64, _lA + 12288);                              \
        ASYNC_LD16(_b,             _lB);                                      \
        ASYNC_LD16(_b + rst64,     _lB + 4096);                               \
        ASYNC_LD16(_b + 2 * rst64, _lB + 8192);                               \
        ASYNC_LD16(_b + 3 * rst64, _lB + 12288);                              \
    } while (0)

    // ---- fragment reads: frag(row, kk) = 8 bf16 at k = kk*32 + lq*8
    // logical chunk = kk*4 + lq; stored chunk = logical ^ ((row>>1)&7);
    // row = (wr*128|wc*64) + t*16 + fr => (row>>1)&7 == (fr>>1)&7.
    const int s7 = (fr >> 1) & 7;
    const int offAk0 = (wr * 128 + fr) * 64 + ((0 + lq) ^ s7) * 8;  // + mi*1024
    const int offAk1 = (wr * 128 + fr) * 64 + ((4 + lq) ^ s7) * 8;
    const int offBk0 = 16384 + (wc * 64 + fr) * 64 + ((0 + lq) ^ s7) * 8;  // + ni*1024
    const int offBk1 = 16384 + (wc * 64 + fr) * 64 + ((4 + lq) ^ s7) * 8;

    f32x4 acc[8][4] = {};
    const int NT = K >> 6;              // K-tiles of 64 (16 or 64 here)

    // prologue: stage tiles 0,1
    STG(0, 0);
    STG(1, 1);
    asm volatile("s_waitcnt vmcnt(8)" ::: "memory");   // tile 0 landed
    __builtin_amdgcn_s_barrier();

    s16x8 a0[4], a1[4], b0[4], b1[4];
    for (int c = 0; c < NT; ++c) {
        const u16* sb = lds + (c & 1) * 32768;
        // ---- ph0 pre: own frags (lo,k0 + B k0) and ph1 frags (lo,k1 + B k1)
#pragma unroll
        for (int i = 0; i < 4; ++i) a0[i] = *(const s16x8*)(sb + offAk0 + i * 1024);
#pragma unroll
        for (int i = 0; i < 4; ++i) b0[i] = *(const s16x8*)(sb + offBk0 + i * 1024);
#pragma unroll
        for (int i = 0; i < 4; ++i) a1[i] = *(const s16x8*)(sb + offAk1 + i * 1024);
#pragma unroll
        for (int i = 0; i < 4; ++i) b1[i] = *(const s16x8*)(sb + offBk1 + i * 1024);
        __builtin_amdgcn_s_barrier();
        __builtin_amdgcn_s_setprio(1);
#pragma unroll
        for (int mi = 0; mi < 4; ++mi)
#pragma unroll
            for (int ni = 0; ni < 4; ++ni)
                acc[mi][ni] = __builtin_amdgcn_mfma_f32_16x16x32_bf16(
                    a0[mi], b0[ni], acc[mi][ni], 0, 0, 0);
        __builtin_amdgcn_s_setprio(0);
        __builtin_amdgcn_s_barrier();
        // ---- ph1 pre: ph2 frags (A hi,k0) -> a0
#pragma unroll
        for (int i = 0; i < 4; ++i) a0[i] = *(const s16x8*)(sb + offAk0 + (i + 4) * 1024);
        __builtin_amdgcn_s_barrier();
        __builtin_amdgcn_s_setprio(1);
#pragma unroll
        for (int mi = 0; mi < 4; ++mi)
#pragma unroll
            for (int ni = 0; ni < 4; ++ni)
                acc[mi][ni] = __builtin_amdgcn_mfma_f32_16x16x32_bf16(
                    a1[mi], b1[ni], acc[mi][ni], 0, 0, 0);
        __builtin_amdgcn_s_setprio(0);
        __builtin_amdgcn_s_barrier();
        // ---- ph2 pre: ph3 frags (A hi,k1) -> a1
#pragma unroll
        for (int i = 0; i < 4; ++i) a1[i] = *(const s16x8*)(sb + offAk1 + (i + 4) * 1024);
        __builtin_amdgcn_s_barrier();
        __builtin_amdgcn_s_setprio(1);
#pragma unroll
        for (int mi = 0; mi < 4; ++mi)
#pragma unroll
            for (int ni = 0; ni < 4; ++ni)
                acc[mi + 4][ni] = __builtin_amdgcn_mfma_f32_16x16x32_bf16(
                    a0[mi], b0[ni], acc[mi + 4][ni], 0, 0, 0);
        __builtin_amdgcn_s_setprio(0);
        __builtin_amdgcn_s_barrier();
        // ---- ph3 pre: stage tile c+2 into buf c&1; counted vmcnt
        if (c + 2 < NT) {
            STG(c & 1, c + 2);
            asm volatile("s_waitcnt vmcnt(8)" ::: "memory");
        } else {
            asm volatile("s_waitcnt vmcnt(0)" ::: "memory");
        }
        __builtin_amdgcn_s_barrier();
        __builtin_amdgcn_s_setprio(1);
#pragma unroll
        for (int mi = 0; mi < 4; ++mi)
#pragma unroll
            for (int ni = 0; ni < 4; ++ni)
                acc[mi + 4][ni] = __builtin_amdgcn_mfma_f32_16x16x32_bf16(
                    a1[mi], b1[ni], acc[mi + 4][ni], 0, 0, 0);
        __builtin_amdgcn_s_setprio(0);
        __builtin_amdgcn_s_barrier();
    }
#undef STG

    // epilogue. C/D layout: row = lq*4 + reg (+16*mi), col = fr (+16*ni)
    const int rowB = m0 + wr * 128 + lq * 4;
    const int colB = n0 + wc * 64 + fr;

    if constexpr (MODE == 2) {
        float inv[4];
#pragma unroll
        for (int ni = 0; ni < 4; ++ni) inv[ni] = 1.0f / sv[colB + ni * 16];
#pragma unroll
        for (int mi = 0; mi < 8; ++mi)
#pragma unroll
            for (int r = 0; r < 4; ++r) {
                const int gm = rowB + mi * 16 + r;
                float s = 0.f;
#pragma unroll
                for (int ni = 0; ni < 4; ++ni) {
                    float e = __expf(acc[mi][ni][r] * inv[ni]);
                    C[(size_t)gm * N + (colB + ni * 16)] = f2bf(e);
                    s += e;
                }
                s += __shfl_xor(s, 1);
                s += __shfl_xor(s, 2);
                s += __shfl_xor(s, 4);
                s += __shfl_xor(s, 8);
                if (fr == 0) atomicAdd(&sum_out[gm], s);
            }
    } else {  // MODE 3: fp32 out, divide by row sum
#pragma unroll
        for (int mi = 0; mi < 8; ++mi)
#pragma unroll
            for (int r = 0; r < 4; ++r) {
                const int gm = rowB + mi * 16 + r;
                const float invr = 1.0f / sv[gm];
#pragma unroll
                for (int ni = 0; ni < 4; ++ni)
                    Cf[(size_t)gm * N + (colB + ni * 16)] = acc[mi][ni][r] * invr;
            }
    }
}

extern "C" void kernel_launch(void* const* d_in, const int* in_sizes, int n_in,
                              void* d_out, int out_size, void* d_ws, size_t ws_size,
                              hipStream_t stream)
{
    (void)in_sizes; (void)n_in; (void)out_size;
    const float* kin = (const float*)d_in[0];   // 32768 x 1024 fp32
    const float* mem = (const float*)d_in[1];   // 4096 x 512
    const float* fkw = (const float*)d_in[2];   // 1024 x 512
    const float* fkb = (const float*)d_in[3];   // 1024
    const float* fvw = (const float*)d_in[4];   // 1024 x 512
    const float* fvb = (const float*)d_in[5];   // 1024
    float* out = (float*)d_out;                 // 32768 x 1024 fp32

    const int NM = 4096, MD = 512, ID = 1024, NQ = 32768;

    u16* kbf   = (u16*)d_ws;                          // NQ x ID   (64 MB)
    u16* membf = kbf   + (size_t)NQ * ID;             // NM x MD   (4 MB)
    u16* fkwbf = membf + (size_t)NM * MD;             // ID x MD   (1 MB)
    u16* fvwbf = fkwbf + (size_t)ID * MD;             // ID x MD   (1 MB)
    u16* expK  = fvwbf + (size_t)ID * MD;             // NM x ID   (8 MB)
    u16* valT  = expK  + (size_t)NM * ID;             // ID x NM   (8 MB)
    u16* P     = valT  + (size_t)ID * NM;             // NQ x NM   (256 MB)
    float* rsK = (float*)(P + (size_t)NQ * NM);       // NM
    float* rs2 = rsK + NM;                            // NQ
    const size_t needed = (size_t)((char*)(rs2 + NQ) - (char*)d_ws);
    if (ws_size < needed) return;  // diagnostic: absmax == 0.2676 exactly

    hipMemsetAsync(rsK, 0, (size_t)(NM + NQ) * sizeof(float), stream);

    // fp32 -> bf16 converts
    cvt_f32_bf16<<<(NQ * ID / 4 + 255) / 256, 256, 0, stream>>>(kin, kbf, NQ * ID / 4);
    cvt_f32_bf16<<<(NM * MD / 4 + 255) / 256, 256, 0, stream>>>(mem, membf, NM * MD / 4);
    cvt_f32_bf16<<<(ID * MD / 4 + 255) / 256, 256, 0, stream>>>(fkw, fkwbf, ID * MD / 4);
    cvt_f32_bf16<<<(ID * MD / 4 + 255) / 256, 256, 0, stream>>>(fvw, fvwbf, ID * MD / 4);

    // K1a: expK[m,i] = exp(mem @ fk_w^T + fk_b[i]); rsK[m] = row sums
    gemm_bt<0><<<dim3(ID / 128, NM / 128), 256, 0, stream>>>(
        membf, fkwbf, MD, ID, expK, nullptr, fkb, nullptr, rsK);
    // K1b: valT[i,m] = relu(fv_w @ mem^T + fv_b[i])
    gemm_bt<1><<<dim3(NM / 128, ID / 128), 256, 0, stream>>>(
        fvwbf, membf, MD, NM, valT, nullptr, fvb, nullptr, nullptr);
    // K2: P[q,m] = exp((k @ expK^T)[q,m] / rsK[m]); rs2[q] = row sums
    gemm256_bt<2><<<(NQ / 256) * (NM / 256), 512, 0, stream>>>(
        kbf, expK, ID, NM, P, nullptr, rsK, rs2, NM / 256);
    // K3: out[q,i] = (P @ valT^T)[q,i] / rs2[q]
    gemm256_bt<3><<<(NQ / 256) * (ID / 256), 512, 0, stream>>>(
        P, valT, NM, ID, nullptr, out, rs2, nullptr, ID / 256);
}